// Round 1
// baseline (12912.666 us; speedup 1.0000x reference)
//
#include <hip/hip_runtime.h>
#include <cmath>

// ---- problem constants ----
#define NB 16
#define CC 32          // channels per dictionary (A and B each)
#define HH 256
#define WW 256
#define DD 250         // 256 - 7 + 1
#define KK 7
#define ALPHA 2.0f     // 1 + 1/RHO
#define INVL 0.1f      // 1/L
#define THR 0.01f      // LAM/L

#define IMG_SZ (HH*WW)             // 65536
#define IMG_TOT (NB*IMG_SZ)        // 1,048,576
#define FLD_SZ (DD*DD)             // 62,500
#define FLD_TOT (NB*CC*FLD_SZ)     // 32,000,000

// ---------------------------------------------------------------------------
// k_update: for every field element (n,c,p,q) of BOTH x (c<32) and u (c>=32):
//   tmp   = first ? 0 : s_cur + cmom*(s_cur - s_old)
//   v     = tmp + conv(res, W_c)[p,q] / L        (forward VALID correlation)
//   v     = (u-field) ? softthresh(v, THR) : v
//   s_next = v            (s_next aliases s_old buffer; 1:1 read-then-write)
// Tile: one (n,c) per block-z, 32 rows x 64 cols of output per block.
// res tile (38 x 70) staged in LDS; 8 output rows per thread.
// ---------------------------------------------------------------------------
__global__ __launch_bounds__(256) void k_update(
    const float* __restrict__ rin,         // res (or y at step 0): [NB][256][256]
    const float* sx_cur, const float* sx_old,
    const float* su_cur, const float* su_old,
    float* sx_next, float* su_next,        // alias sx_old/su_old
    const float* __restrict__ Afil, const float* __restrict__ Bfil,
    float cmom, int first)
{
    __shared__ float lres[38*70];
    __shared__ float wf[49];

    const int z  = blockIdx.z;
    const int n  = z >> 6;
    const int c  = z & 63;
    const int p0 = blockIdx.y * 32;
    const int q0 = blockIdx.x * 64;
    const int tid = threadIdx.x;

    const bool isx = (c < CC);
    const int  cf  = isx ? c : (c - CC);
    const float* Wp = isx ? (Afil + cf*49) : (Bfil + cf*49);
    if (tid < 49) wf[tid] = Wp[tid];

    const float* rbase = rin + (size_t)n * IMG_SZ;
    for (int idx = tid; idx < 38*70; idx += 256) {
        int r  = idx / 70;
        int cc2 = idx - r*70;
        int gr = p0 + r, gc = q0 + cc2;
        float v = 0.0f;
        if (gr < HH && gc < WW) v = rbase[gr*WW + gc];
        lres[idx] = v;
    }
    __syncthreads();

    const int tq = tid & 63;
    const int pg = tid >> 6;          // 0..3, each covers 8 output rows

    float acc[8];
#pragma unroll
    for (int i = 0; i < 8; ++i) acc[i] = 0.0f;

#pragma unroll
    for (int b = 0; b < 7; ++b) {
        float wa[7];
#pragma unroll
        for (int a = 0; a < 7; ++a) wa[a] = wf[a*7 + b];
#pragma unroll
        for (int rr = 0; rr < 14; ++rr) {
            float v = lres[(pg*8 + rr)*70 + tq + b];
#pragma unroll
            for (int a = 0; a < 7; ++a) {
                int k = rr - a;
                if (k >= 0 && k < 8) acc[k] += v * wa[a];
            }
        }
    }

    const int q = q0 + tq;
    if (q < DD) {
        const float* scur  = isx ? sx_cur  : su_cur;
        const float* sold  = isx ? sx_old  : su_old;
        float*       snext = isx ? sx_next : su_next;
        const size_t base = ((size_t)(n*CC + cf)) * FLD_SZ;
#pragma unroll
        for (int k = 0; k < 8; ++k) {
            int p = p0 + pg*8 + k;
            if (p < DD) {
                size_t off = base + (size_t)p*DD + q;
                float tmp = 0.0f;
                if (!first) {
                    float sc = scur[off], so = sold[off];
                    tmp = sc + cmom * (sc - so);
                }
                float v = tmp + acc[k] * INVL;
                if (!isx) {
                    float av = fabsf(v) - THR;
                    av = av > 0.0f ? av : 0.0f;
                    v = (v > 0.0f) ? av : ((v < 0.0f) ? -av : 0.0f);
                }
                snext[off] = v;
            }
        }
    }
}

// ---------------------------------------------------------------------------
// k_convT: X[n,h,w] = sum_c sum_{a,b} s[n,c,h-a,w-b] * W[c,a,b]  (adjoint)
// One (n, field) per block-z; 32(h) x 64(w) output tile; channels staged in
// LDS 2 at a time, zero-padded so there are no boundary branches inside.
// ---------------------------------------------------------------------------
__global__ __launch_bounds__(256) void k_convT(
    const float* __restrict__ sx, const float* __restrict__ su,
    float* __restrict__ Xout, float* __restrict__ Uout,
    const float* __restrict__ Afil, const float* __restrict__ Bfil)
{
    __shared__ float st[2*38*70];
    __shared__ float wf[CC*49];

    const int z  = blockIdx.z;
    const int n  = z >> 1;
    const int f  = z & 1;
    const int h0 = blockIdx.y * 32;
    const int w0 = blockIdx.x * 64;
    const int tid = threadIdx.x;

    const float* S  = f ? su : sx;
    const float* Wp = f ? Bfil : Afil;
    float* O = (f ? Uout : Xout) + (size_t)n * IMG_SZ;

    for (int i = tid; i < CC*49; i += 256) wf[i] = Wp[i];

    const int tw = tid & 63;
    const int hb = tid >> 6;          // 0..3, each covers 8 output rows

    float acc[8];
#pragma unroll
    for (int i = 0; i < 8; ++i) acc[i] = 0.0f;

    for (int c0 = 0; c0 < CC; c0 += 2) {
        __syncthreads();
        for (int idx = tid; idx < 2*38*70; idx += 256) {
            int ch  = idx / (38*70);
            int rem = idx - ch*(38*70);
            int r   = rem / 70;
            int cc2 = rem - r*70;
            int gh = h0 - 6 + r, gw = w0 - 6 + cc2;
            float v = 0.0f;
            if (gh >= 0 && gh < DD && gw >= 0 && gw < DD)
                v = S[((size_t)(n*CC + c0 + ch))*FLD_SZ + (size_t)gh*DD + gw];
            st[idx] = v;
        }
        __syncthreads();
#pragma unroll
        for (int ch = 0; ch < 2; ++ch) {
            const float* wc  = &wf[(c0 + ch)*49];
            const float* stc = &st[ch*38*70];
#pragma unroll
            for (int b = 0; b < 7; ++b) {
                float wa[7];
#pragma unroll
                for (int a = 0; a < 7; ++a) wa[a] = wc[a*7 + b];
#pragma unroll
                for (int rr = 0; rr < 14; ++rr) {
                    float v = stc[(hb*8 + rr)*70 + tw + 6 - b];
#pragma unroll
                    for (int a = 0; a < 7; ++a) {
                        int k = rr - 6 + a;
                        if (k >= 0 && k < 8) acc[k] += v * wa[a];
                    }
                }
            }
        }
    }

#pragma unroll
    for (int k = 0; k < 8; ++k) {
        int h = h0 + hb*8 + k;
        O[(size_t)h*WW + w0 + tw] = acc[k];
    }
}

// ---------------------------------------------------------------------------
// k_res: res = y - ALPHA*((1+c)X_t - c*X_{t-1}) - ((1+c)U_t - c*U_{t-1})
// pure elementwise on the 4-MB images, float4.
// ---------------------------------------------------------------------------
__global__ __launch_bounds__(256) void k_res(
    const float* __restrict__ y,
    const float* __restrict__ Xc, const float* __restrict__ Xo,
    const float* __restrict__ Uc, const float* __restrict__ Uo,
    float* __restrict__ res, float cm)
{
    int i = blockIdx.x*256 + threadIdx.x;
    if (i < IMG_TOT/4) {
        const float4* y4  = (const float4*)y;
        const float4* xc4 = (const float4*)Xc;
        const float4* xo4 = (const float4*)Xo;
        const float4* uc4 = (const float4*)Uc;
        const float4* uo4 = (const float4*)Uo;
        float4 yv = y4[i], xc = xc4[i], xo = xo4[i], uc = uc4[i], uo = uo4[i];
        float cp = 1.0f + cm;
        float4 r;
        r.x = yv.x - ALPHA*(cp*xc.x - cm*xo.x) - (cp*uc.x - cm*uo.x);
        r.y = yv.y - ALPHA*(cp*xc.y - cm*xo.y) - (cp*uc.y - cm*uo.y);
        r.z = yv.z - ALPHA*(cp*xc.z - cm*xo.z) - (cp*uc.z - cm*uo.z);
        r.w = yv.w - ALPHA*(cp*xc.w - cm*xo.w) - (cp*uc.w - cm*uo.w);
        ((float4*)res)[i] = r;
    }
}

// ---------------------------------------------------------------------------
// k_final: y_hat = X + U; Ax_hat = X; Bu_hat = U.
// NOTE: Ax_hat may alias X, Bu_hat may alias U (same index read-then-write,
// safe within a thread).
// ---------------------------------------------------------------------------
__global__ __launch_bounds__(256) void k_final(
    const float* Xi, const float* Ui,
    float* yhat, float* axh, float* buh)
{
    int i = blockIdx.x*256 + threadIdx.x;
    if (i < IMG_TOT/4) {
        float4 x = ((const float4*)Xi)[i];
        float4 u = ((const float4*)Ui)[i];
        float4 s;
        s.x = x.x + u.x; s.y = x.y + u.y; s.z = x.z + u.z; s.w = x.w + u.w;
        ((float4*)yhat)[i] = s;
        ((float4*)axh)[i]  = x;
        ((float4*)buh)[i]  = u;
    }
}

extern "C" void kernel_launch(void* const* d_in, const int* in_sizes, int n_in,
                              void* d_out, int out_size, void* d_ws, size_t ws_size,
                              hipStream_t stream) {
    const float* y = (const float*)d_in[0];
    const float* A = (const float*)d_in[1];
    const float* B = (const float*)d_in[2];

    float* out  = (float*)d_out;
    float* yhat = out;                         // [IMG_TOT]
    float* xout = out + IMG_TOT;               // [FLD_TOT]
    float* uout = xout + FLD_TOT;              // [FLD_TOT]
    float* axh  = uout + FLD_TOT;              // [IMG_TOT]
    float* buh  = axh + IMG_TOT;               // [IMG_TOT]

    float* ws  = (float*)d_ws;                 // needs 2*FLD_TOT + 2*IMG_TOT floats (~264 MB)
    float* Px0 = ws;
    float* Pu0 = ws + FLD_TOT;
    float* Xi0 = ws + 2*(size_t)FLD_TOT;
    float* Ui0 = Xi0 + IMG_TOT;

    // Parity: s_t lives in P[t%2]; s_15 must land in d_out slots -> P1 = d_out.
    float* Px[2] = {Px0, xout};
    float* Pu[2] = {Pu0, uout};
    // Image-space projections X_t = convT(x_t, A), U_t = convT(u_t, B).
    // X_t lives in Xi[t%2]; Xi1/Ui1/res borrow the axh/buh/yhat output slots
    // (all are rewritten by k_final at the very end).
    float* Xi[2] = {Xi0, axh};
    float* Ui[2] = {Ui0, buh};
    float* res   = yhat;

    // FISTA momentum coefficients (fp32, matching the reference recurrence).
    float cv[15];
    {
        float t = 1.0f;
        for (int k = 0; k < 15; ++k) {
            float tn = (1.0f + sqrtf(1.0f + 4.0f*t*t)) * 0.5f;
            cv[k] = (t - 1.0f) / tn;   // cv[0] == 0 exactly
            t = tn;
        }
    }

    dim3 blk(256);
    dim3 gU(4, 8, NB*64);   // q-tiles, p-tiles, n*(2*32 channels)
    dim3 gT(4, 8, NB*2);    // w-tiles, h-tiles, n*fields

    // step 0: res == y, tmp == 0; writes s_1 into P[1] (d_out slots)
    k_update<<<gU, blk, 0, stream>>>(y, Px[0], Px[0], Pu[0], Pu[0],
                                     Px[1], Pu[1], A, B, 0.0f, 1);
    k_convT<<<gT, blk, 0, stream>>>(Px[1], Pu[1], Xi[1], Ui[1], A, B);

    for (int t = 1; t < 15; ++t) {
        int cur = t & 1, nxt = 1 - cur;
        float cm = cv[t-1];
        k_res<<<IMG_TOT/4/256, blk, 0, stream>>>(y, Xi[cur], Xi[nxt], Ui[cur], Ui[nxt], res, cm);
        k_update<<<gU, blk, 0, stream>>>(res, Px[cur], Px[nxt], Pu[cur], Pu[nxt],
                                         Px[nxt], Pu[nxt], A, B, cm, 0);
        k_convT<<<gT, blk, 0, stream>>>(Px[nxt], Pu[nxt], Xi[nxt], Ui[nxt], A, B);
    }

    // s_15 is in P[1] (= d_out x/u slots); X_15/U_15 in Xi[1]/Ui[1] (= axh/buh)
    k_final<<<IMG_TOT/4/256, blk, 0, stream>>>(Xi[1], Ui[1], yhat, axh, buh);
}

// Round 2
// 8918.718 us; speedup vs baseline: 1.4478x; 1.4478x over previous
//
#include <hip/hip_runtime.h>
#include <cmath>

// ---- problem constants ----
#define NB 16
#define CC 32          // channels per dictionary (A and B each)
#define HH 256
#define WW 256
#define DD 250         // 256 - 7 + 1
#define ALPHA 2.0f     // 1 + 1/RHO
#define INVL 0.1f      // 1/L
#define THR 0.01f      // LAM/L

#define IMG_SZ (HH*WW)             // 65536
#define IMG_TOT (NB*IMG_SZ)        // 1,048,576
#define FLD_SZ (DD*DD)             // 62,500
#define FLD_TOT (NB*CC*FLD_SZ)     // 32,000,000

// ---------------------------------------------------------------------------
// k_update v2: block = (channel-group of 8, p-tile of 32 rows, n).
// Full-width tile: stage res rows [p0 .. p0+37] x 256 cols in LDS once,
// loop 8 channels; each thread computes 8 rows x 4 cols with float4 windows.
//   tmp    = first ? 0 : s_cur + cmom*(s_cur - s_old)
//   v      = tmp + conv(res, W_c)[p,q] * INVL
//   v      = (u-field) ? softthresh(v, THR) : v
//   s_next = v     (s_next aliases s_old; same-offset read-then-write)
// NOTE: sx_*/su_* intentionally NOT __restrict__ (snext aliases sold).
// ---------------------------------------------------------------------------
__global__ __launch_bounds__(256) void k_update(
    const float* __restrict__ rin,         // res (or y at step 0): [NB][256][256]
    const float* sx_cur, const float* sx_old,
    const float* su_cur, const float* su_old,
    float* sx_next, float* su_next,
    const float* __restrict__ Afil, const float* __restrict__ Bfil,
    float cmom, int first)
{
    __shared__ float lres[38*256 + 8];     // +8 pad: window overrun of masked lanes
    __shared__ float wf[8*49];

    const int cg  = blockIdx.x;            // 0..7 (0-3: x/A, 4-7: u/B)
    const int p0  = blockIdx.y * 32;
    const int n   = blockIdx.z;
    const int tid = threadIdx.x;

    const bool isx = (cg < 4);
    const int  cg0 = (cg & 3) * 8;         // first channel of this group

    const float* Wsrc = isx ? Afil : Bfil;
    for (int i = tid; i < 392; i += 256) wf[i] = Wsrc[cg0*49 + i];
    if (tid < 8) lres[38*256 + tid] = 0.0f;

    const float* rbase = rin + (size_t)n * IMG_SZ;
    for (int idx = tid; idx < 38*64; idx += 256) {
        int r  = idx >> 6;
        int c4 = (idx & 63) << 2;
        int gr = p0 + r;
        float4 v = make_float4(0.f, 0.f, 0.f, 0.f);
        if (gr < HH) v = *(const float4*)(rbase + gr*WW + c4);
        *(float4*)&lres[r*256 + c4] = v;
    }
    __syncthreads();

    const int tq = tid & 63;
    const int pg = tid >> 6;               // 0..3, 8 output rows each
    const int q4 = tq << 2;

    const float* scur  = isx ? sx_cur  : su_cur;
    const float* sold  = isx ? sx_old  : su_old;
    float*       snext = isx ? sx_next : su_next;

    for (int ch = 0; ch < 8; ++ch) {
        float wt[7][7];
#pragma unroll
        for (int a = 0; a < 7; ++a)
#pragma unroll
            for (int b = 0; b < 7; ++b)
                wt[a][b] = wf[ch*49 + a*7 + b];

        float acc[8][4];
#pragma unroll
        for (int k = 0; k < 8; ++k)
#pragma unroll
            for (int j = 0; j < 4; ++j) acc[k][j] = 0.0f;

#pragma unroll
        for (int rr = 0; rr < 14; ++rr) {
            const float4* lp = (const float4*)&lres[(pg*8 + rr)*256 + q4];
            float4 A0 = lp[0], A1 = lp[1], A2 = lp[2];
            float win[12] = {A0.x,A0.y,A0.z,A0.w, A1.x,A1.y,A1.z,A1.w,
                             A2.x,A2.y,A2.z,A2.w};
#pragma unroll
            for (int a = 0; a < 7; ++a) {
                int k = rr - a;
                if (k >= 0 && k < 8) {
#pragma unroll
                    for (int b = 0; b < 7; ++b) {
                        float wv = wt[a][b];
#pragma unroll
                        for (int j = 0; j < 4; ++j)
                            acc[k][j] += win[b + j] * wv;
                    }
                }
            }
        }

        const size_t base = ((size_t)n*CC + (cg0 + ch)) * FLD_SZ;
#pragma unroll
        for (int k = 0; k < 8; ++k) {
            int p = p0 + pg*8 + k;
            if (p < DD) {
                size_t off = base + (size_t)p*DD + q4;
                if (q4 <= 248) {           // cols q4, q4+1
                    float t0 = 0.f, t1 = 0.f;
                    if (!first) {
                        float2 sc = *(const float2*)(scur + off);
                        float2 so = *(const float2*)(sold + off);
                        t0 = sc.x + cmom*(sc.x - so.x);
                        t1 = sc.y + cmom*(sc.y - so.y);
                    }
                    float v0 = t0 + acc[k][0]*INVL;
                    float v1 = t1 + acc[k][1]*INVL;
                    if (!isx) {
                        float a0 = fabsf(v0) - THR; a0 = a0 > 0.f ? a0 : 0.f;
                        v0 = (v0 > 0.f) ? a0 : ((v0 < 0.f) ? -a0 : 0.f);
                        float a1 = fabsf(v1) - THR; a1 = a1 > 0.f ? a1 : 0.f;
                        v1 = (v1 > 0.f) ? a1 : ((v1 < 0.f) ? -a1 : 0.f);
                    }
                    *(float2*)(snext + off) = make_float2(v0, v1);
                }
                if (q4 <= 246) {           // cols q4+2, q4+3
                    float t2 = 0.f, t3 = 0.f;
                    if (!first) {
                        float2 sc = *(const float2*)(scur + off + 2);
                        float2 so = *(const float2*)(sold + off + 2);
                        t2 = sc.x + cmom*(sc.x - so.x);
                        t3 = sc.y + cmom*(sc.y - so.y);
                    }
                    float v2 = t2 + acc[k][2]*INVL;
                    float v3 = t3 + acc[k][3]*INVL;
                    if (!isx) {
                        float a2 = fabsf(v2) - THR; a2 = a2 > 0.f ? a2 : 0.f;
                        v2 = (v2 > 0.f) ? a2 : ((v2 < 0.f) ? -a2 : 0.f);
                        float a3 = fabsf(v3) - THR; a3 = a3 > 0.f ? a3 : 0.f;
                        v3 = (v3 > 0.f) ? a3 : ((v3 < 0.f) ? -a3 : 0.f);
                    }
                    *(float2*)(snext + off + 2) = make_float2(v2, v3);
                }
            }
        }
    }
}

// ---------------------------------------------------------------------------
// k_convT v2: X[n,h,w] = sum_c sum_{a,b} s[n,c,h-a,w-b] * W[c,a,b]
// Block = (h-tile of 16 rows, field, n); full 256-col width.
// Per channel: stage s rows [h0-6 .. h0+15] into a zero-padded 22x264 LDS
// plane (cols 0..5 and 256..263 are permanent zeros -> no boundary branches
// in the compute loop). Thread: 4 rows x 4 cols, float4 windows/stores.
// ---------------------------------------------------------------------------
__global__ __launch_bounds__(256) void k_convT(
    const float* __restrict__ sx, const float* __restrict__ su,
    float* __restrict__ Xout, float* __restrict__ Uout,
    const float* __restrict__ Afil, const float* __restrict__ Bfil)
{
    __shared__ float st[22*264];
    __shared__ float wf[CC*49];

    const int h0  = blockIdx.x * 16;
    const int f   = blockIdx.y;
    const int n   = blockIdx.z;
    const int tid = threadIdx.x;

    const float* S  = f ? su : sx;
    const float* Wp = f ? Bfil : Afil;
    float* O = (f ? Uout : Xout) + (size_t)n * IMG_SZ;

    for (int i = tid; i < CC*49; i += 256) wf[i] = Wp[i];
    for (int i = tid; i < 22*14; i += 256) {       // permanent zero borders
        int r = i / 14, j = i - r*14;
        int col = (j < 6) ? j : (250 + j);         // cols 0..5, 256..263
        st[r*264 + col] = 0.0f;
    }

    const int tw = tid & 63;
    const int hg = tid >> 6;               // 0..3, 4 output rows each
    const int w4 = tw << 2;

    float acc[4][4];
#pragma unroll
    for (int k = 0; k < 4; ++k)
#pragma unroll
        for (int j = 0; j < 4; ++j) acc[k][j] = 0.0f;

    const float* Sn = S + ((size_t)n*CC) * FLD_SZ;

    for (int c = 0; c < CC; ++c) {
        __syncthreads();                   // prev compute done (also covers init)
        const float* Sp = Sn + (size_t)c * FLD_SZ;
        for (int i = tid; i < 22*125; i += 256) {  // float2 granularity
            int r = i / 125, j = i - r*125;
            int sr = h0 - 6 + r;
            float2 v = make_float2(0.f, 0.f);
            if (sr >= 0 && sr < DD) v = *(const float2*)(Sp + (size_t)sr*DD + 2*j);
            *(float2*)&st[r*264 + 6 + 2*j] = v;
        }
        __syncthreads();

        float wt[7][7];
#pragma unroll
        for (int a = 0; a < 7; ++a)
#pragma unroll
            for (int b = 0; b < 7; ++b)
                wt[a][b] = wf[c*49 + a*7 + b];

#pragma unroll
        for (int rr = 0; rr < 10; ++rr) {
            const float4* lp = (const float4*)&st[(hg*4 + rr)*264 + w4];
            float4 A0 = lp[0], A1 = lp[1], A2 = lp[2];
            float win[12] = {A0.x,A0.y,A0.z,A0.w, A1.x,A1.y,A1.z,A1.w,
                             A2.x,A2.y,A2.z,A2.w};
#pragma unroll
            for (int k = 0; k < 4; ++k) {
                int a = k + 6 - rr;
                if (a >= 0 && a < 7) {
#pragma unroll
                    for (int t = 0; t < 7; ++t) {
                        float wv = wt[a][6 - t];
#pragma unroll
                        for (int j = 0; j < 4; ++j)
                            acc[k][j] += win[j + t] * wv;
                    }
                }
            }
        }
    }

#pragma unroll
    for (int k = 0; k < 4; ++k) {
        int h = h0 + hg*4 + k;
        *(float4*)(O + (size_t)h*WW + w4) =
            make_float4(acc[k][0], acc[k][1], acc[k][2], acc[k][3]);
    }
}

// ---------------------------------------------------------------------------
// k_res: res = y - ALPHA*((1+c)X_t - c*X_{t-1}) - ((1+c)U_t - c*U_{t-1})
// ---------------------------------------------------------------------------
__global__ __launch_bounds__(256) void k_res(
    const float* __restrict__ y,
    const float* __restrict__ Xc, const float* __restrict__ Xo,
    const float* __restrict__ Uc, const float* __restrict__ Uo,
    float* __restrict__ res, float cm)
{
    int i = blockIdx.x*256 + threadIdx.x;
    if (i < IMG_TOT/4) {
        float4 yv = ((const float4*)y)[i];
        float4 xc = ((const float4*)Xc)[i];
        float4 xo = ((const float4*)Xo)[i];
        float4 uc = ((const float4*)Uc)[i];
        float4 uo = ((const float4*)Uo)[i];
        float cp = 1.0f + cm;
        float4 r;
        r.x = yv.x - ALPHA*(cp*xc.x - cm*xo.x) - (cp*uc.x - cm*uo.x);
        r.y = yv.y - ALPHA*(cp*xc.y - cm*xo.y) - (cp*uc.y - cm*uo.y);
        r.z = yv.z - ALPHA*(cp*xc.z - cm*xo.z) - (cp*uc.z - cm*uo.z);
        r.w = yv.w - ALPHA*(cp*xc.w - cm*xo.w) - (cp*uc.w - cm*uo.w);
        ((float4*)res)[i] = r;
    }
}

// ---------------------------------------------------------------------------
// k_final: y_hat = X + U; Ax_hat = X; Bu_hat = U (aliasing-safe: same index).
// ---------------------------------------------------------------------------
__global__ __launch_bounds__(256) void k_final(
    const float* Xi, const float* Ui,
    float* yhat, float* axh, float* buh)
{
    int i = blockIdx.x*256 + threadIdx.x;
    if (i < IMG_TOT/4) {
        float4 x = ((const float4*)Xi)[i];
        float4 u = ((const float4*)Ui)[i];
        float4 s;
        s.x = x.x + u.x; s.y = x.y + u.y; s.z = x.z + u.z; s.w = x.w + u.w;
        ((float4*)yhat)[i] = s;
        ((float4*)axh)[i]  = x;
        ((float4*)buh)[i]  = u;
    }
}

extern "C" void kernel_launch(void* const* d_in, const int* in_sizes, int n_in,
                              void* d_out, int out_size, void* d_ws, size_t ws_size,
                              hipStream_t stream) {
    const float* y = (const float*)d_in[0];
    const float* A = (const float*)d_in[1];
    const float* B = (const float*)d_in[2];

    float* out  = (float*)d_out;
    float* yhat = out;                         // [IMG_TOT]
    float* xout = out + IMG_TOT;               // [FLD_TOT]
    float* uout = xout + FLD_TOT;              // [FLD_TOT]
    float* axh  = uout + FLD_TOT;              // [IMG_TOT]
    float* buh  = axh + IMG_TOT;               // [IMG_TOT]

    float* ws  = (float*)d_ws;                 // 2*FLD_TOT + 2*IMG_TOT floats (~264 MB)
    float* Px0 = ws;
    float* Pu0 = ws + FLD_TOT;
    float* Xi0 = ws + 2*(size_t)FLD_TOT;
    float* Ui0 = Xi0 + IMG_TOT;

    // Parity: s_t in P[t%2]; s_15 must land in d_out -> P1 = d_out slots.
    float* Px[2] = {Px0, xout};
    float* Pu[2] = {Pu0, uout};
    // Image-space projections X_t = convT(x_t, A), U_t = convT(u_t, B).
    // Xi1/Ui1/res borrow axh/buh/yhat (rewritten by k_final at the end).
    float* Xi[2] = {Xi0, axh};
    float* Ui[2] = {Ui0, buh};
    float* res   = yhat;

    // FISTA momentum coefficients (cv[0] == 0 exactly -> no init needed:
    // uninitialized s_old is multiplied by 0.0 and 0xAA.. floats are finite).
    float cv[15];
    {
        float t = 1.0f;
        for (int k = 0; k < 15; ++k) {
            float tn = (1.0f + sqrtf(1.0f + 4.0f*t*t)) * 0.5f;
            cv[k] = (t - 1.0f) / tn;
            t = tn;
        }
    }

    dim3 blk(256);
    dim3 gU(8, 8, NB);      // (channel-group, p-tile, n)
    dim3 gT(16, 2, NB);     // (h-tile, field, n)

    // step 0: res == y, tmp == 0; writes s_1 into P[1] (d_out slots)
    k_update<<<gU, blk, 0, stream>>>(y, Px[0], Px[0], Pu[0], Pu[0],
                                     Px[1], Pu[1], A, B, 0.0f, 1);
    k_convT<<<gT, blk, 0, stream>>>(Px[1], Pu[1], Xi[1], Ui[1], A, B);

    for (int t = 1; t < 15; ++t) {
        int cur = t & 1, nxt = 1 - cur;
        float cm = cv[t-1];
        k_res<<<IMG_TOT/4/256, blk, 0, stream>>>(y, Xi[cur], Xi[nxt], Ui[cur], Ui[nxt], res, cm);
        k_update<<<gU, blk, 0, stream>>>(res, Px[cur], Px[nxt], Pu[cur], Pu[nxt],
                                         Px[nxt], Pu[nxt], A, B, cm, 0);
        k_convT<<<gT, blk, 0, stream>>>(Px[nxt], Pu[nxt], Xi[nxt], Ui[nxt], A, B);
    }

    k_final<<<IMG_TOT/4/256, blk, 0, stream>>>(Xi[1], Ui[1], yhat, axh, buh);
}

// Round 3
// 7667.394 us; speedup vs baseline: 1.6841x; 1.1632x over previous
//
#include <hip/hip_runtime.h>
#include <cmath>

// ---- problem constants ----
#define NB 16
#define CC 32          // channels per dictionary (A and B each)
#define HH 256
#define WW 256
#define DD 250         // 256 - 7 + 1
#define ALPHA 2.0f     // 1 + 1/RHO
#define INVL 0.1f      // 1/L
#define THR 0.01f      // LAM/L

#define IMG_SZ (HH*WW)                       // 65536
#define IMG_TOT (NB*IMG_SZ)                  // 1,048,576
#define FLD_SZ (DD*DD)                       // 62,500
#define FLD_TOT ((size_t)NB*CC*FLD_SZ)       // 32,000,000

// force a block-uniform float into an SGPR (weights): v_fma_f32 can take one
// SGPR operand, so filter taps in SGPRs cut VGPR pressure massively.
__device__ __forceinline__ float rfl(float x) {
    return __int_as_float(__builtin_amdgcn_readfirstlane(__float_as_int(x)));
}

// ---------------------------------------------------------------------------
// k_update v3: ONE channel per block. grid = (64 ch, 16 ptiles, 16 n).
// Stage res rows [p0..p0+21] x 256 in LDS; weights -> SGPR; thread computes
// 4 rows x 4 cols. tmp = s_cur + cm*(s_cur - s_old); v = tmp + conv*INVL;
// u-field soft-threshold; s_next (aliases s_old) = v.
// ---------------------------------------------------------------------------
__global__ __launch_bounds__(256) void k_update(
    const float* __restrict__ rin,
    const float* sx_cur, const float* sx_old,
    const float* su_cur, const float* su_old,
    float* sx_next, float* su_next,
    const float* __restrict__ Afil, const float* __restrict__ Bfil,
    float cmom, int first)
{
    __shared__ float lres[22*256 + 8];       // +8: window overrun of masked lanes

    const int c   = blockIdx.x;              // 0..63 (0-31: x/A, 32-63: u/B)
    const int p0  = blockIdx.y * 16;
    const int n   = blockIdx.z;
    const int tid = threadIdx.x;
    const bool isx = (c < CC);
    const int  cf  = isx ? c : c - CC;

    const float* rbase = rin + (size_t)n * IMG_SZ;
#pragma unroll
    for (int it = 0; it < 6; ++it) {
        int idx = tid + it*256;
        if (idx < 22*64) {
            int r = idx >> 6, c4 = (idx & 63) << 2;
            int gr = p0 + r;
            float4 v = make_float4(0.f,0.f,0.f,0.f);
            if (gr < HH) v = *(const float4*)(rbase + gr*WW + c4);
            *(float4*)&lres[r*256 + c4] = v;
        }
    }

    const float* Wp = (isx ? Afil : Bfil) + cf*49;
    float wt[7][7];
#pragma unroll
    for (int a = 0; a < 7; ++a)
#pragma unroll
        for (int b = 0; b < 7; ++b)
            wt[a][b] = rfl(Wp[a*7 + b]);

    __syncthreads();

    const int tq = tid & 63;
    const int pg = tid >> 6;                 // one wave == one row group
    const int q4 = tq << 2;

    float acc[4][4];
#pragma unroll
    for (int k = 0; k < 4; ++k)
#pragma unroll
        for (int j = 0; j < 4; ++j) acc[k][j] = 0.f;

#pragma unroll
    for (int rr = 0; rr < 10; ++rr) {
        const float4* lp = (const float4*)&lres[(pg*4 + rr)*256 + q4];
        float4 A0 = lp[0], A1 = lp[1], A2 = lp[2];
        float win[12] = {A0.x,A0.y,A0.z,A0.w, A1.x,A1.y,A1.z,A1.w,
                         A2.x,A2.y,A2.z,A2.w};
#pragma unroll
        for (int k = 0; k < 4; ++k) {
            const int a = rr - k;            // res row p+a <-> lds row pg*4+k+a
            if (a >= 0 && a < 7) {
#pragma unroll
                for (int b = 0; b < 7; ++b) {
                    float wv = wt[a][b];
#pragma unroll
                    for (int j = 0; j < 4; ++j)
                        acc[k][j] += win[b + j] * wv;
                }
            }
        }
    }

    const float* scur  = isx ? sx_cur  : su_cur;
    const float* sold  = isx ? sx_old  : su_old;
    float*       snext = isx ? sx_next : su_next;
    const size_t base = ((size_t)n*CC + cf) * FLD_SZ;
    const bool momentum = (!first) && (cmom != 0.0f);
    const bool plain    = (!first) && (cmom == 0.0f);

#pragma unroll
    for (int k = 0; k < 4; ++k) {
        int p = p0 + pg*4 + k;
        if (p < DD) {
            size_t off = base + (size_t)p*DD + q4;
            if (q4 <= 248) {                 // cols q4, q4+1
                float t0 = 0.f, t1 = 0.f;
                if (momentum) {
                    float2 sc = *(const float2*)(scur + off);
                    float2 so = *(const float2*)(sold + off);
                    t0 = sc.x + cmom*(sc.x - so.x);
                    t1 = sc.y + cmom*(sc.y - so.y);
                } else if (plain) {          // cm==0: don't touch (garbage) s_old
                    float2 sc = *(const float2*)(scur + off);
                    t0 = sc.x; t1 = sc.y;
                }
                float v0 = t0 + acc[k][0]*INVL;
                float v1 = t1 + acc[k][1]*INVL;
                if (!isx) {
                    float a0 = fabsf(v0) - THR; a0 = a0 > 0.f ? a0 : 0.f;
                    v0 = (v0 > 0.f) ? a0 : ((v0 < 0.f) ? -a0 : 0.f);
                    float a1 = fabsf(v1) - THR; a1 = a1 > 0.f ? a1 : 0.f;
                    v1 = (v1 > 0.f) ? a1 : ((v1 < 0.f) ? -a1 : 0.f);
                }
                *(float2*)(snext + off) = make_float2(v0, v1);
            }
            if (q4 <= 246) {                 // cols q4+2, q4+3
                float t2 = 0.f, t3 = 0.f;
                if (momentum) {
                    float2 sc = *(const float2*)(scur + off + 2);
                    float2 so = *(const float2*)(sold + off + 2);
                    t2 = sc.x + cmom*(sc.x - so.x);
                    t3 = sc.y + cmom*(sc.y - so.y);
                } else if (plain) {
                    float2 sc = *(const float2*)(scur + off + 2);
                    t2 = sc.x; t3 = sc.y;
                }
                float v2 = t2 + acc[k][2]*INVL;
                float v3 = t3 + acc[k][3]*INVL;
                if (!isx) {
                    float a2 = fabsf(v2) - THR; a2 = a2 > 0.f ? a2 : 0.f;
                    v2 = (v2 > 0.f) ? a2 : ((v2 < 0.f) ? -a2 : 0.f);
                    float a3 = fabsf(v3) - THR; a3 = a3 > 0.f ? a3 : 0.f;
                    v3 = (v3 > 0.f) ? a3 : ((v3 < 0.f) ? -a3 : 0.f);
                }
                *(float2*)(snext + off + 2) = make_float2(v2, v3);
            }
        }
    }
}

// ---------------------------------------------------------------------------
// k_convT v3: X[h,w] = sum_c sum_{a,b} s[c,h-a,w-b] W[c,a,b], channel-group
// split across blocks (nc channels each, ngroups partials per field).
// grid = (16 htiles, 2 fields, NB*ngroups). Zero-padded 22x264 LDS plane per
// channel; weights in SGPRs; thread = 4 rows x 4 cols; float4 store.
// Partial layout: part[g][n][IMG_SZ].
// ---------------------------------------------------------------------------
__global__ __launch_bounds__(256) void k_convT(
    const float* __restrict__ sx, const float* __restrict__ su,
    float* __restrict__ Xpart, float* __restrict__ Upart,
    const float* __restrict__ Afil, const float* __restrict__ Bfil,
    int nc, int ngroups)
{
    __shared__ float st[22*264];

    const int h0  = blockIdx.x * 16;
    const int f   = blockIdx.y;
    const int zz  = blockIdx.z;
    const int g   = zz % ngroups;
    const int n   = zz / ngroups;
    const int c0  = g * nc;
    const int tid = threadIdx.x;

    const float* Sn = (f ? su : sx) + (size_t)n*CC*FLD_SZ;
    const float* Wb = f ? Bfil : Afil;
    float* O = (f ? Upart : Xpart) + ((size_t)g*NB + n) * IMG_SZ;

    for (int i = tid; i < 22*14; i += 256) {     // permanent zero borders
        int r = i / 14, j = i - r*14;
        st[r*264 + (j < 6 ? j : 250 + j)] = 0.f;
    }

    const int tw = tid & 63;
    const int hg = tid >> 6;
    const int w4 = tw << 2;

    float acc[4][4];
#pragma unroll
    for (int k = 0; k < 4; ++k)
#pragma unroll
        for (int j = 0; j < 4; ++j) acc[k][j] = 0.f;

    for (int cc2 = 0; cc2 < nc; ++cc2) {
        const int c = c0 + cc2;
        __syncthreads();                         // prev compute done
        const float* Sp = Sn + (size_t)c * FLD_SZ;
        for (int i = tid; i < 22*125; i += 256) {
            int r = i / 125, j = i - r*125;
            int sr = h0 - 6 + r;
            float2 v = make_float2(0.f, 0.f);
            if (sr >= 0 && sr < DD) v = *(const float2*)(Sp + (size_t)sr*DD + 2*j);
            *(float2*)&st[r*264 + 6 + 2*j] = v;
        }
        float wt[7][7];
#pragma unroll
        for (int a = 0; a < 7; ++a)
#pragma unroll
            for (int b = 0; b < 7; ++b)
                wt[a][b] = rfl(Wb[c*49 + a*7 + b]);
        __syncthreads();

#pragma unroll
        for (int rr = 0; rr < 10; ++rr) {
            const float4* lp = (const float4*)&st[(hg*4 + rr)*264 + w4];
            float4 A0 = lp[0], A1 = lp[1], A2 = lp[2];
            float win[12] = {A0.x,A0.y,A0.z,A0.w, A1.x,A1.y,A1.z,A1.w,
                             A2.x,A2.y,A2.z,A2.w};
#pragma unroll
            for (int k = 0; k < 4; ++k) {
                const int a = k + 6 - rr;        // lds row r = h - a - h0 + 6
                if (a >= 0 && a < 7) {
#pragma unroll
                    for (int b = 0; b < 7; ++b) {
                        float wv = wt[a][b];
#pragma unroll
                        for (int j = 0; j < 4; ++j)
                            acc[k][j] += win[j - b + 6] * wv;
                    }
                }
            }
        }
    }

#pragma unroll
    for (int k = 0; k < 4; ++k) {
        int h = h0 + hg*4 + k;
        *(float4*)(O + (size_t)h*WW + w4) =
            make_float4(acc[k][0], acc[k][1], acc[k][2], acc[k][3]);
    }
}

// ---------------------------------------------------------------------------
// k_res: reduce partials -> Xc/Uc; read compacts (prev gen) as Xo/Uo; write
// compacts := Xc/Uc (same-index read-then-write, safe); emit res.
// ---------------------------------------------------------------------------
__global__ __launch_bounds__(256) void k_res(
    const float* __restrict__ y,
    const float* __restrict__ Xp, const float* __restrict__ Up,
    float* Xred, float* Ured,
    float* __restrict__ res, float cm, int nparts)
{
    int i = blockIdx.x*256 + threadIdx.x;
    if (i >= IMG_TOT/4) return;
    float4 xc = ((const float4*)Xp)[i];
    float4 uc = ((const float4*)Up)[i];
    for (int g = 1; g < nparts; ++g) {
        float4 t = ((const float4*)Xp)[(size_t)g*(IMG_TOT/4) + i];
        xc.x += t.x; xc.y += t.y; xc.z += t.z; xc.w += t.w;
        float4 s = ((const float4*)Up)[(size_t)g*(IMG_TOT/4) + i];
        uc.x += s.x; uc.y += s.y; uc.z += s.z; uc.w += s.w;
    }
    float4 xo = make_float4(0.f,0.f,0.f,0.f), uo = xo;
    if (cm != 0.0f) {                        // cm==0: compacts hold garbage
        xo = ((const float4*)Xred)[i];
        uo = ((const float4*)Ured)[i];
    }
    ((float4*)Xred)[i] = xc;
    ((float4*)Ured)[i] = uc;
    float4 yv = ((const float4*)y)[i];
    float cp = 1.0f + cm;
    float4 r;
    r.x = yv.x - ALPHA*(cp*xc.x - cm*xo.x) - (cp*uc.x - cm*uo.x);
    r.y = yv.y - ALPHA*(cp*xc.y - cm*xo.y) - (cp*uc.y - cm*uo.y);
    r.z = yv.z - ALPHA*(cp*xc.z - cm*xo.z) - (cp*uc.z - cm*uo.z);
    r.w = yv.w - ALPHA*(cp*xc.w - cm*xo.w) - (cp*uc.w - cm*uo.w);
    ((float4*)res)[i] = r;
}

// ---------------------------------------------------------------------------
// k_final: reduce gen-15 partials; yhat = X+U; Ax_hat = X; Bu_hat = U.
// In fallback mode Xp==axh / Up==buh: reads complete before writes (thread-
// local same-index), safe.
// ---------------------------------------------------------------------------
__global__ __launch_bounds__(256) void k_final(
    const float* Xp, const float* Up,
    float* yhat, float* axh, float* buh, int nparts)
{
    int i = blockIdx.x*256 + threadIdx.x;
    if (i >= IMG_TOT/4) return;
    float4 x = ((const float4*)Xp)[i];
    float4 u = ((const float4*)Up)[i];
    for (int g = 1; g < nparts; ++g) {
        float4 t = ((const float4*)Xp)[(size_t)g*(IMG_TOT/4) + i];
        x.x += t.x; x.y += t.y; x.z += t.z; x.w += t.w;
        float4 s = ((const float4*)Up)[(size_t)g*(IMG_TOT/4) + i];
        u.x += s.x; u.y += s.y; u.z += s.z; u.w += s.w;
    }
    float4 sm;
    sm.x = x.x + u.x; sm.y = x.y + u.y; sm.z = x.z + u.z; sm.w = x.w + u.w;
    ((float4*)yhat)[i] = sm;
    ((float4*)axh)[i]  = x;
    ((float4*)buh)[i]  = u;
}

extern "C" void kernel_launch(void* const* d_in, const int* in_sizes, int n_in,
                              void* d_out, int out_size, void* d_ws, size_t ws_size,
                              hipStream_t stream) {
    const float* y = (const float*)d_in[0];
    const float* A = (const float*)d_in[1];
    const float* B = (const float*)d_in[2];

    float* out  = (float*)d_out;
    float* yhat = out;                          // [IMG_TOT]
    float* xout = out + IMG_TOT;                // [FLD_TOT]
    float* uout = xout + FLD_TOT;               // [FLD_TOT]
    float* axh  = uout + FLD_TOT;               // [IMG_TOT]
    float* buh  = axh + IMG_TOT;                // [IMG_TOT]

    float* ws   = (float*)d_ws;
    float* Px0  = ws;                           // [FLD_TOT]
    float* Pu0  = Px0 + FLD_TOT;                // [FLD_TOT]
    float* Xred = Pu0 + FLD_TOT;                // [IMG_TOT] compact prev-gen X
    float* Ured = Xred + IMG_TOT;               // [IMG_TOT] compact prev-gen U

    // convT channel split: 4 groups if ws has room for 8 partial images,
    // else fall back to unsplit partials borrowed from d_out (same kernels).
    int ngroups = 1;
    float* Xpart = axh;
    float* Upart = buh;
    size_t need4 = (2*FLD_TOT + 10*(size_t)IMG_TOT) * sizeof(float); // 296 MB
    if (ws_size >= need4) {
        ngroups = 4;
        Xpart = Ured + IMG_TOT;                 // [4*IMG_TOT]
        Upart = Xpart + 4*(size_t)IMG_TOT;      // [4*IMG_TOT]
    }
    const int nc = CC / ngroups;

    // FISTA momentum coefficients (cv[0] == 0 exactly).
    float cv[15];
    {
        float t = 1.0f;
        for (int k = 0; k < 15; ++k) {
            float tn = (1.0f + sqrtf(1.0f + 4.0f*t*t)) * 0.5f;
            cv[k] = (t - 1.0f) / tn;
            t = tn;
        }
    }

    // Parity: s_t in P[t&1]; s_15 (odd) lands in d_out slots = P[1].
    float* Px[2] = {Px0, xout};
    float* Pu[2] = {Pu0, uout};
    float* res   = yhat;                        // borrowed, rewritten by k_final

    dim3 blk(256);
    dim3 gU(64, 16, NB);                        // (channel, p-tile, n)
    dim3 gT(16, 2, NB*ngroups);                 // (h-tile, field, n*group)
    int  gE = (IMG_TOT/4 + 255)/256;

    // step 0: res == y, tmp == 0; writes s_1 into P[1]
    k_update<<<gU, blk, 0, stream>>>(y, Px[0], Px[0], Pu[0], Pu[0],
                                     Px[1], Pu[1], A, B, 0.0f, 1);
    k_convT<<<gT, blk, 0, stream>>>(Px[1], Pu[1], Xpart, Upart, A, B, nc, ngroups);

    for (int t = 1; t < 15; ++t) {
        int cur = t & 1, nxt = cur ^ 1;
        float cm = cv[t-1];
        k_res<<<gE, blk, 0, stream>>>(y, Xpart, Upart, Xred, Ured, res, cm, ngroups);
        k_update<<<gU, blk, 0, stream>>>(res, Px[cur], Px[nxt], Pu[cur], Pu[nxt],
                                         Px[nxt], Pu[nxt], A, B, cm, 0);
        k_convT<<<gT, blk, 0, stream>>>(Px[nxt], Pu[nxt], Xpart, Upart, A, B, nc, ngroups);
    }

    k_final<<<gE, blk, 0, stream>>>(Xpart, Upart, yhat, axh, buh, ngroups);
}